// Round 5
// baseline (241.390 us; speedup 1.0000x reference)
//
#include <hip/hip_runtime.h>

#define NN 1024
#define HH 512
#define TR 32
#define TC 32
#define S1R 70          // stage-1 rows needed: 2*(TR-1)+8
#define XST 74          // EVEN -> 8B-aligned b64 window reads, 4 lanes/bank-pair (free)
#define NF4 18          // float4 loads per row (logical cols 0..71)
#define NLD 5           // ceil(70*18/256) load slots per thread
#define ADS 36          // A/D plane stride: b128-aligned, quad-group (9u+cg)%8 uniform (free)
#define TILES 4         // vertical tiles per block, 1-ahead prefetch pipeline

typedef float f2  __attribute__((ext_vector_type(2)));
typedef float f4v __attribute__((ext_vector_type(4)));

// acc.lo += ab.lo*w.lo ; acc.hi += ab.hi*w.lo   (broadcast LOW half of w)
__device__ __forceinline__ void pk_fma_blo(f2& acc, f2 ab, f2 w) {
    asm("v_pk_fma_f32 %0, %1, %2, %0 op_sel:[0,0,0] op_sel_hi:[1,0,1]"
        : "+v"(acc) : "v"(ab), "v"(w));
}
// acc.lo += ab.lo*w.hi ; acc.hi += ab.hi*w.hi   (broadcast HIGH half of w)
__device__ __forceinline__ void pk_fma_bhi(f2& acc, f2 ab, f2 w) {
    asm("v_pk_fma_f32 %0, %1, %2, %0 op_sel:[0,1,0] op_sel_hi:[1,1,1]"
        : "+v"(acc) : "v"(ab), "v"(w));
}

__global__ __launch_bounds__(256, 4) void dwt2d_fused(const float* __restrict__ x,
                                                      const float* __restrict__ bmt,
                                                      float* __restrict__ out) {
    __shared__ float Xs[S1R][XST];   // 20,720 B (physical col = logical col - 1)
    __shared__ float As[S1R][ADS];   // 10,080 B
    __shared__ float Ds[S1R][ADS];   // 10,080 B   (total 40,880 -> 4 blk/CU)

    const int tid = threadIdx.x;
    const int b  = blockIdx.z;
    const int Rb = blockIdx.y * (TILES * TR);   // this block's 4 tiles: R0 = Rb + t*32
    const int C0 = blockIdx.x * TC;

    // lohi[j] = (dec_lo[j], dec_hi[j]); dec_lo[j]=bmt[7-j], dec_hi[j]=bmt[j]*(j odd ? +1 : -1)
    f2 lohi[8];
#pragma unroll
    for (int j = 0; j < 8; ++j) {
        float l = bmt[7 - j];
        float vv = bmt[j];
        f2 p; p.x = l; p.y = (j & 1) ? vv : -vv;
        lohi[j] = p;
    }

    const float* xb = x + (size_t)b * NN * NN;
    const int pb = 2 * C0 - 4;                  // f4-aligned global col base

    // ---- tile-invariant phase-1 mapping: idx -> (row-in-patch u, col, Xs slot)
    int su[NLD], gcol[NLD], qq[NLD];
    bool wr[NLD];
#pragma unroll
    for (int k = 0; k < NLD; ++k) {
        int idx = tid + 256 * k;
        unsigned uu = (unsigned)idx / 18u;
        int tt = idx - 18 * (int)uu;
        su[k]   = (int)uu;
        gcol[k] = (pb + 4 * tt) & (NN - 1);
        qq[k]   = 4 * tt - 1;                   // physical base col in Xs
        wr[k]   = idx < S1R * NF4;
    }

    // ---- prologue: load + stage tile 0
    {
        const int rbase = 2 * Rb - 3;
        float4 v[NLD];
#pragma unroll
        for (int k = 0; k < NLD; ++k) {
            int row = (rbase + su[k]) & (NN - 1);
            v[k] = *(const float4*)(xb + ((size_t)row << 10) + gcol[k]);
        }
#pragma unroll
        for (int k = 0; k < NLD; ++k) {
            if (wr[k]) {
                int u = su[k], q = qq[k];
                if (q >= 0) Xs[u][q] = v[k].x;
                f2 yz; yz.x = v[k].y; yz.y = v[k].z;
                *(f2*)&Xs[u][q + 1] = yz;       // q+1 = 4t: 8B-aligned
                Xs[u][q + 3] = v[k].w;
            }
        }
    }
    __syncthreads();

#pragma unroll 1
    for (int t = 0; t < TILES; ++t) {
        const int R0 = Rb + t * TR;

        // ---- prefetch tile t+1 into registers (issued BEFORE phase-2 so the
        // ~900cy HBM latency hides under phase-2's LDS/VALU work).
        float4 vn[NLD];
        if (t < TILES - 1) {
            const int rbase = 2 * (R0 + TR) - 3;
#pragma unroll
            for (int k = 0; k < NLD; ++k) {
                int row = (rbase + su[k]) & (NN - 1);
                vn[k] = *(const float4*)(xb + ((size_t)row << 10) + gcol[k]);
            }
        }

        // ---- phase 2: stage-1 filter (Xs -> As/Ds), packed (a,d) accumulation.
        for (int pos = tid; pos < S1R * 8; pos += 256) {
            int u  = pos >> 3;
            int c0 = (pos & 7) * 4;
            const f2* wrow = (const f2*)&Xs[u][2 * c0];   // even offset -> 8B aligned
            f2 w2[7];
#pragma unroll
            for (int q = 0; q < 7; ++q) w2[q] = wrow[q];
            f2 accs[4];
#pragma unroll
            for (int m = 0; m < 4; ++m) {
                f2 acc; acc.x = 0.f; acc.y = 0.f;
#pragma unroll
                for (int s = 0; s < 4; ++s) {
                    pk_fma_blo(acc, lohi[2 * s],     w2[m + s]);   // j=2s   tap
                    pk_fma_bhi(acc, lohi[2 * s + 1], w2[m + s]);   // j=2s+1 tap
                }
                accs[m] = acc;
            }
            f4v va, vd;
            va.x = accs[0].x; va.y = accs[1].x; va.z = accs[2].x; va.w = accs[3].x;
            vd.x = accs[0].y; vd.y = accs[1].y; vd.z = accs[2].y; vd.w = accs[3].y;
            *(f4v*)&As[u][c0] = va;             // b128, conflict-free
            *(f4v*)&Ds[u][c0] = vd;
        }
        __syncthreads();                        // phase2 done: Xs now dead, As/Ds ready

        // ---- refill Xs with tile t+1 (overlaps phase-3 below in the scheduler)
        if (t < TILES - 1) {
#pragma unroll
            for (int k = 0; k < NLD; ++k) {
                if (wr[k]) {
                    int u = su[k], q = qq[k];
                    if (q >= 0) Xs[u][q] = vn[k].x;
                    f2 yz; yz.x = vn[k].y; yz.y = vn[k].z;
                    *(f2*)&Xs[u][q + 1] = yz;
                    Xs[u][q + 3] = vn[k].w;
                }
            }
        }

        // ---- phase 3: stage-2 filter (along rows); 4 quadrants; b128 reads.
        const int cg = tid & 7;
        const int r  = tid >> 3;
        f2 acc0[4], acc1[4];                    // acc0[i]=(aa,ad), acc1[i]=(da,dd)
#pragma unroll
        for (int i = 0; i < 4; ++i) {
            acc0[i].x = 0.f; acc0[i].y = 0.f;
            acc1[i].x = 0.f; acc1[i].y = 0.f;
        }
#pragma unroll
        for (int j = 0; j < 8; ++j) {
            f4v qa = *(const f4v*)&As[2 * r + j][4 * cg];   // quad-group uniform -> free
            f4v qd = *(const f4v*)&Ds[2 * r + j][4 * cg];
            f2 lh = lohi[j];
            f2 a01 = qa.xy, a23 = qa.zw, d01 = qd.xy, d23 = qd.zw;
            pk_fma_blo(acc0[0], lh, a01);
            pk_fma_bhi(acc0[1], lh, a01);
            pk_fma_blo(acc0[2], lh, a23);
            pk_fma_bhi(acc0[3], lh, a23);
            pk_fma_blo(acc1[0], lh, d01);
            pk_fma_bhi(acc1[1], lh, d01);
            pk_fma_blo(acc1[2], lh, d23);
            pk_fma_bhi(acc1[3], lh, d23);
        }
        float* ob = out + (size_t)b * NN * NN;
        const int orow = R0 + r;
        const int ocol = C0 + 4 * cg;
        f4v s0; s0.x = acc0[0].x; s0.y = acc0[1].x; s0.z = acc0[2].x; s0.w = acc0[3].x;
        f4v s1; s1.x = acc0[0].y; s1.y = acc0[1].y; s1.z = acc0[2].y; s1.w = acc0[3].y;
        f4v s2; s2.x = acc1[0].x; s2.y = acc1[1].x; s2.z = acc1[2].x; s2.w = acc1[3].x;
        f4v s3; s3.x = acc1[0].y; s3.y = acc1[1].y; s3.z = acc1[2].y; s3.w = acc1[3].y;
        *(f4v*)(ob + (size_t)orow * NN + ocol)             = s0;
        *(f4v*)(ob + (size_t)orow * NN + ocol + HH)        = s1;
        *(f4v*)(ob + (size_t)(orow + HH) * NN + ocol)      = s2;
        *(f4v*)(ob + (size_t)(orow + HH) * NN + ocol + HH) = s3;

        __syncthreads();   // Xs refill visible to all; As/Ds reads done before next phase2
    }
}

extern "C" void kernel_launch(void* const* d_in, const int* in_sizes, int n_in,
                              void* d_out, int out_size, void* d_ws, size_t ws_size,
                              hipStream_t stream) {
    const float* x   = (const float*)d_in[0];
    const float* bmt = (const float*)d_in[1];
    float* out = (float*)d_out;
    const int B = in_sizes[0] / (NN * NN);        // 32
    dim3 grid(HH / TC, HH / (TR * TILES), B);     // 16 x 4 x 32 = 2048 blocks
    dwt2d_fused<<<grid, 256, 0, stream>>>(x, bmt, out);
}

// Round 7
// 234.857 us; speedup vs baseline: 1.0278x; 1.0278x over previous
//
#include <hip/hip_runtime.h>

#define NN 1024
#define HH 512
#define TR 32
#define TC 32
#define S1R 70          // stage-1 rows staged: 2*(TR-1)+8
#define XST 82          // stride ≡ 2 (mod 16): fused-phase b64 reads 2-way/bank-pair = free
#define NF4 18          // float4 loads per row (logical cols 0..71)
#define NLD 5           // ceil(70*18/256) load slots per thread

typedef float f2  __attribute__((ext_vector_type(2)));
typedef float f4v __attribute__((ext_vector_type(4)));

// acc.lo += ab.lo*w.lo ; acc.hi += ab.hi*w.lo   (broadcast LOW half of w)
__device__ __forceinline__ void pk_fma_blo(f2& acc, f2 ab, f2 w) {
    asm("v_pk_fma_f32 %0, %1, %2, %0 op_sel:[0,0,0] op_sel_hi:[1,0,1]"
        : "+v"(acc) : "v"(ab), "v"(w));
}
// acc.lo += ab.lo*w.hi ; acc.hi += ab.hi*w.hi   (broadcast HIGH half of w)
__device__ __forceinline__ void pk_fma_bhi(f2& acc, f2 ab, f2 w) {
    asm("v_pk_fma_f32 %0, %1, %2, %0 op_sel:[0,1,0] op_sel_hi:[1,1,1]"
        : "+v"(acc) : "v"(ab), "v"(w));
}

__global__ __launch_bounds__(256, 7) void dwt2d_fused(const float* __restrict__ x,
                                                      const float* __restrict__ bmt,
                                                      float* __restrict__ out) {
    // ONLY Xs is staged. Stage-1 results are recomputed per output row (VALU has
    // 5x headroom); As/Ds round-trip and 2nd barrier eliminated.
    __shared__ float Xs[S1R][XST];   // 70 x 82 x 4B = 22,960 B -> 7 blk/CU (28 waves, 87%)

    const int tid = threadIdx.x;
    const int b  = blockIdx.z;
    const int R0 = blockIdx.y * TR;
    const int C0 = blockIdx.x * TC;

    // lohi[j] = (dec_lo[j], dec_hi[j]); dec_lo[j]=bmt[7-j], dec_hi[j]=bmt[j]*(j odd ? +1 : -1)
    f2 lohi[8];
#pragma unroll
    for (int j = 0; j < 8; ++j) {
        float l = bmt[7 - j];
        float vv = bmt[j];
        f2 p; p.x = l; p.y = (j & 1) ? vv : -vv;
        lohi[j] = p;
    }

    const float* xb = x + (size_t)b * NN * NN;
    const int rbase = 2 * R0 - 3;        // patch row u -> x row (rbase+u) & 1023
    const int pb    = 2 * C0 - 4;        // logical patch col p -> x col (pb+p) & 1023 (f4-aligned)

    // ---- phase 1: load 70 x 18 float4s (wrapped, aligned, unconditional), store SHIFTED by -1.
    // (physical col = logical col - 1, so 8-tap windows start at EVEN offsets -> b64 reads)
    float4 v[NLD];
    int    su[NLD], st4[NLD];
#pragma unroll
    for (int k = 0; k < NLD; ++k) {
        int idx = tid + 256 * k;
        unsigned uu = (unsigned)idx / 18u;
        int tt = idx - 18 * (int)uu;
        su[k] = (int)uu; st4[k] = tt;
        int row = (rbase + (int)uu) & (NN - 1);
        int gc  = (pb + 4 * tt) & (NN - 1);
        v[k] = *(const float4*)(xb + ((size_t)row << 10) + gc);
    }
#pragma unroll
    for (int k = 0; k < NLD; ++k) {
        int idx = tid + 256 * k;
        if (idx < S1R * NF4) {
            int u = su[k];
            int q = 4 * st4[k] - 1;              // physical base col
            if (q >= 0) Xs[u][q] = v[k].x;       // logical col 0 never used
            f2 yz; yz.x = v[k].y; yz.y = v[k].z;
            *(f2*)&Xs[u][q + 1] = yz;            // q+1 = 4t: 8B-aligned b64 write
            Xs[u][q + 3] = v[k].w;
        }
    }
    __syncthreads();                             // the ONLY barrier

    // ---- fused stage-1 + stage-2, fully thread-private.
    // Thread (r = tid>>3, cg = tid&7) owns output row R0+r, cols C0+4cg..+3, all 4 quadrants.
    // For each tap j: stage-1 row u = 2r+j, read 14 floats (7 aligned b64) at phys col 8cg,
    // compute packed (a,d)[m] (32 pk_fma), immediately fold into stage-2 accs (8 pk_fma).
    const int cg = tid & 7;
    const int r  = tid >> 3;
    f2 acc0[4], acc1[4];                         // acc0[m]=(aa,ad), acc1[m]=(da,dd)
#pragma unroll
    for (int i = 0; i < 4; ++i) {
        acc0[i].x = 0.f; acc0[i].y = 0.f;
        acc1[i].x = 0.f; acc1[i].y = 0.f;
    }
#pragma unroll
    for (int j = 0; j < 8; ++j) {
        const f2* wrow = (const f2*)&Xs[2 * r + j][8 * cg];   // even phys col -> 8B aligned
        f2 w2[7];
#pragma unroll
        for (int t = 0; t < 7; ++t) w2[t] = wrow[t];          // 2-way bank pairs = free
        f2 lh = lohi[j];
#pragma unroll
        for (int m = 0; m < 4; ++m) {
            f2 ad; ad.x = 0.f; ad.y = 0.f;                    // stage-1 (a,d) for col c0+m
#pragma unroll
            for (int s = 0; s < 4; ++s) {
                pk_fma_blo(ad, lohi[2 * s],     w2[m + s]);   // tap j1=2s   (w.x)
                pk_fma_bhi(ad, lohi[2 * s + 1], w2[m + s]);   // tap j1=2s+1 (w.y)
            }
            pk_fma_blo(acc0[m], lh, ad);   // (aa,ad) += (lo_j,hi_j) * a
            pk_fma_bhi(acc1[m], lh, ad);   // (da,dd) += (lo_j,hi_j) * d
        }
    }
    float* ob = out + (size_t)b * NN * NN;
    const int orow = R0 + r;
    const int ocol = C0 + 4 * cg;
    f4v s0; s0.x = acc0[0].x; s0.y = acc0[1].x; s0.z = acc0[2].x; s0.w = acc0[3].x;
    f4v s1; s1.x = acc0[0].y; s1.y = acc0[1].y; s1.z = acc0[2].y; s1.w = acc0[3].y;
    f4v s2; s2.x = acc1[0].x; s2.y = acc1[1].x; s2.z = acc1[2].x; s2.w = acc1[3].x;
    f4v s3; s3.x = acc1[0].y; s3.y = acc1[1].y; s3.z = acc1[2].y; s3.w = acc1[3].y;
    *(f4v*)(ob + (size_t)orow * NN + ocol)             = s0;
    *(f4v*)(ob + (size_t)orow * NN + ocol + HH)        = s1;
    *(f4v*)(ob + (size_t)(orow + HH) * NN + ocol)      = s2;
    *(f4v*)(ob + (size_t)(orow + HH) * NN + ocol + HH) = s3;
}

extern "C" void kernel_launch(void* const* d_in, const int* in_sizes, int n_in,
                              void* d_out, int out_size, void* d_ws, size_t ws_size,
                              hipStream_t stream) {
    const float* x   = (const float*)d_in[0];
    const float* bmt = (const float*)d_in[1];
    float* out = (float*)d_out;
    const int B = in_sizes[0] / (NN * NN);   // 32
    dim3 grid(HH / TC, HH / TR, B);          // 16 x 16 x 32 = 8192 blocks
    dwt2d_fused<<<grid, 256, 0, stream>>>(x, bmt, out);
}